// Round 4
// baseline (1679.425 us; speedup 1.0000x reference)
//
#include <hip/hip_runtime.h>
#include <cstdint>
#include <math.h>

#define B_  64
#define L_  256
#define V_  256
#define E_  256
#define H_  1024
#define H3  3072

typedef __bf16 bf16x8 __attribute__((ext_vector_type(8)));
typedef float  f32x4  __attribute__((ext_vector_type(4)));

__device__ __forceinline__ unsigned short f2bf(float f) {
    union { float f; unsigned u; } v; v.f = f;
    unsigned r = v.u + 0x7fffu + ((v.u >> 16) & 1u);   // round-to-nearest-even
    return (unsigned short)(r >> 16);
}

// ok iff NO 16-bit half of any dword equals the 0xAAAA poison sentinel
__device__ __forceinline__ int chunk_ok(bf16x8 v) {
    union { bf16x8 b; unsigned u[4]; } cv; cv.b = v;
    int ok = 1;
#pragma unroll
    for (int i = 0; i < 4; i++) {
        unsigned x = cv.u[i] ^ 0xAAAAAAAAu;
        ok &= (int)((x & 0xFFFFu) != 0u) & (int)((x >> 16) != 0u);
    }
    return ok;
}

// ---- single prep kernel: 3 transposes + emb convert + h0 zero + hist poison ----
// grid regions: [0,3072) WhT tiles; [3072,3840) WiT; [3840,4096) WoutT;
// [4096,4352) embB+h0 (+ctl zero); [4352,12544) poison slots 1..256.
__global__ __launch_bounds__(256) void prep_all(
        const float* __restrict__ Wh, const float* __restrict__ Wi,
        const float* __restrict__ Wout, const float* __restrict__ emb,
        unsigned short* __restrict__ WhT, unsigned short* __restrict__ WiT,
        unsigned short* __restrict__ WoutT, unsigned short* __restrict__ embB,
        unsigned short* __restrict__ h0b, uint4* __restrict__ poison,
        int* __restrict__ ctl) {
    __shared__ unsigned short tile[32][34];
    int bid = blockIdx.x;
    const float* src; unsigned short* dst; int rows, cols, nt, kt;
    if (bid < 3072)      { src = Wh;   dst = WhT;   rows = H_; cols = H3; nt = bid % 96; kt = bid / 96; }
    else if (bid < 3840) { int b = bid - 3072; src = Wi;   dst = WiT;   rows = E_; cols = H3; nt = b % 96; kt = b / 96; }
    else if (bid < 4096) { int b = bid - 3840; src = Wout; dst = WoutT; rows = H_; cols = V_; nt = b % 8;  kt = b / 8; }
    else if (bid < 4352) {
        int idx = (bid - 4096) * 256 + threadIdx.x;   // 65536 = V*E = B*H
        embB[idx] = f2bf(emb[idx]);
        h0b[idx]  = 0;
        if (bid == 4096 && threadIdx.x < 16) ctl[threadIdx.x] = 0;
        return;
    } else {
        size_t T = (size_t)(bid - 4352) * 256 + threadIdx.x;   // 2M uint4 = 33.55 MB
        uint4 v; v.x = v.y = v.z = v.w = 0xAAAAAAAAu;
        poison[T] = v;
        return;
    }
    int n0 = nt * 32, k0 = kt * 32;
    int tx = threadIdx.x & 31, ty = threadIdx.x >> 5;
#pragma unroll
    for (int j = 0; j < 32; j += 8)
        tile[tx][ty + j] = f2bf(src[(size_t)(k0 + ty + j) * cols + (n0 + tx)]);
    __syncthreads();
#pragma unroll
    for (int j = 0; j < 32; j += 8)
        dst[(size_t)(n0 + ty + j) * rows + (k0 + tx)] = tile[ty + j][tx];
}

// ---- phase 2: persistent GRU with XCD-local dataflow via HW_REG_XCC_ID ----
// 8 groups (one per XCD) x 32 members. Group g owns batch rows [8g,8g+8);
// member m owns h-cols [32m,32m+32). Membership comes from the HARDWARE XCD
// id + atomic rendezvous (no mapping assumption); overflow blocks take
// deficit slots after a bounded grid barrier.
// Handoff: dual same-address stores (sc0 -> local L2; sc0 sc1 -> L3). Both
// write identical bytes so ordering is irrelevant. Consumers poll sc0 (L2
// fast path) with a STICKY per-wave fallback to sc0 sc1 after 64 misses —
// degrades to round-0 behavior if grouping is ever wrong; never stale,
// never hangs (all spins bounded -> fail loud via absmax).
__global__ __launch_bounds__(256, 1) void gru_persistent(
        unsigned short* __restrict__ hist,        // [257][B][H], slot0=0, rest poisoned
        const unsigned short* __restrict__ WhT,   // [3H][H]
        const unsigned short* __restrict__ WiT,   // [3H][E]
        const unsigned short* __restrict__ embB,  // [V][E]
        const int* __restrict__ tokens,           // [B][L]
        const float* __restrict__ bh,
        unsigned short* __restrict__ yB,          // [B][L][H]
        int* __restrict__ ctl) {                  // [0..7]=xcd ctrs, [8]=ovf, [9]=bar
    // slots 0..7 used; 11 slots (90KB) force 1 block/CU so the dispatcher
    // deals exactly 32 blocks per XCD.
    __shared__ f32x4 red[2][4][11][64];
    __shared__ int s_gm[2];

    int wave = threadIdx.x >> 6, lane = threadIdx.x & 63;
    int l16 = lane & 15, q = lane >> 4;

    // ---- rendezvous: hardware XCD id -> (group, member) ----
    if (threadIdx.x == 0) {
        unsigned xcd;
        asm volatile("s_getreg_b32 %0, hwreg(HW_REG_XCC_ID)" : "=s"(xcd));
        xcd &= 7u;
        int slot = atomicAdd(&ctl[xcd], 1);
        int g, m, ovf = -1;
        if (slot < 32) { g = (int)xcd; m = slot; }
        else { ovf = atomicAdd(&ctl[8], 1); g = 0; m = 0; }
        atomicAdd(&ctl[9], 1);                    // barrier arrival (all blocks)
        if (ovf >= 0) {
            int spins = 0;
            while (atomicAdd(&ctl[9], 0) < 256 && ++spins < (1 << 22))
                __builtin_amdgcn_s_sleep(8);
            int idx = 0;
            for (int x = 0; x < 8; x++) {
                int c = atomicAdd(&ctl[x], 0); if (c > 32) c = 32;
                for (int mm = c; mm < 32; mm++) {
                    if (idx == ovf) { g = x; m = mm; }
                    idx++;
                }
            }
        }
        s_gm[0] = g; s_gm[1] = m;
    }
    __syncthreads();
    const int g = s_gm[0], m = s_gm[1];
    const int b0 = g * 8;
    const int jbase = m * 32;
    const int kbase = wave * 256;

    // ---- pin Wh fragments: [jt][gate][kk]  (48 x bf16x8 = 192 VGPR) ----
    bf16x8 Wreg[2][3][8];
#pragma unroll
    for (int jt = 0; jt < 2; jt++)
#pragma unroll
        for (int gt = 0; gt < 3; gt++) {
            const bf16x8* Brow = (const bf16x8*)(WhT + (size_t)(gt * H_ + jbase + jt * 16 + l16) * H_);
#pragma unroll
            for (int kk = 0; kk < 8; kk++) {
                Wreg[jt][gt][kk] = Brow[(kbase >> 3) + kk * 4 + q];
                asm volatile("" : "+v"(Wreg[jt][gt][kk]));
            }
        }
    // ---- pin Wi fragments: [jt][gate][c]  (12 x bf16x8 = 48 VGPR) ----
    bf16x8 Wxreg[2][3][2];
#pragma unroll
    for (int jt = 0; jt < 2; jt++)
#pragma unroll
        for (int gt = 0; gt < 3; gt++) {
            const bf16x8* Bx = (const bf16x8*)(WiT + (size_t)(gt * H_ + jbase + jt * 16 + l16) * E_);
#pragma unroll
            for (int c = 0; c < 2; c++) {
                Wxreg[jt][gt][c] = Bx[wave * 8 + c * 4 + q];
                asm volatile("" : "+v"(Wxreg[jt][gt][c]));
            }
        }

    // ---- epilogue mapping: thread -> (row, jcol); valid rows 0..7 ----
    int Lp  = lane;
    int reg = wave;
    int erow = (Lp >> 4) * 4 + reg;               // C/D row
    int act  = (erow < 8);
    int jcol = Lp & 15;
    int b    = b0 + erow;
    float bhv[2][3];
#pragma unroll
    for (int jt = 0; jt < 2; jt++) {
        int j = jbase + jt * 16 + jcol;
        bhv[jt][0] = bh[j];
        bhv[jt][1] = bh[H_ + j];
        bhv[jt][2] = bh[2 * H_ + j];
    }
    float hreg[2] = {0.0f, 0.0f};

    const int tokrow = (b0 + (l16 & 7)) * L_;     // A-row (aliased for l16>=8)
    const int pact = (l16 < 8);                   // only 8 valid A-rows load/poll
    int coh = 0;                                  // sticky coherent-poll fallback (wave-uniform)

    bf16x8 a0, a1, a2, a3, a4, a5, a6, a7;

    for (int t = 0; t < L_; t++) {
        const unsigned short* hist_t  = hist + (size_t)t * (B_ * H_);
        unsigned short*       hist_t1 = hist + (size_t)(t + 1) * (B_ * H_);
        const unsigned short* p = hist_t + (size_t)(b0 + (l16 & 7)) * H_ + kbase + q * 8;

        // ---- issue poll group A (chunks 0-3) first; xw MFMAs run in shadow ----
        if (pact) {
            if (coh) {
                asm volatile("global_load_dwordx4 %0, %1, off sc0 sc1" : "=v"(a0) : "v"(p));
                asm volatile("global_load_dwordx4 %0, %1, off sc0 sc1" : "=v"(a1) : "v"(p + 32));
                asm volatile("global_load_dwordx4 %0, %1, off sc0 sc1" : "=v"(a2) : "v"(p + 64));
                asm volatile("global_load_dwordx4 %0, %1, off sc0 sc1" : "=v"(a3) : "v"(p + 96));
            } else {
                asm volatile("global_load_dwordx4 %0, %1, off sc0" : "=v"(a0) : "v"(p));
                asm volatile("global_load_dwordx4 %0, %1, off sc0" : "=v"(a1) : "v"(p + 32));
                asm volatile("global_load_dwordx4 %0, %1, off sc0" : "=v"(a2) : "v"(p + 64));
                asm volatile("global_load_dwordx4 %0, %1, off sc0" : "=v"(a3) : "v"(p + 96));
            }
        }

        // ---- xw partials seeded into accumulators (h-independent) ----
        int tok = tokens[tokrow + t];
        const bf16x8* Ax = (const bf16x8*)(embB + (size_t)tok * E_);
        bf16x8 ax0 = Ax[wave * 8 + q];
        bf16x8 ax1 = Ax[wave * 8 + 4 + q];
        f32x4 accr[2] = {}, accz[2] = {}, acchn[2] = {}, accxn[2] = {};
#pragma unroll
        for (int jt = 0; jt < 2; jt++) {
            accr[jt]  = __builtin_amdgcn_mfma_f32_16x16x32_bf16(ax0, Wxreg[jt][0][0], accr[jt], 0, 0, 0);
            accr[jt]  = __builtin_amdgcn_mfma_f32_16x16x32_bf16(ax1, Wxreg[jt][0][1], accr[jt], 0, 0, 0);
            accz[jt]  = __builtin_amdgcn_mfma_f32_16x16x32_bf16(ax0, Wxreg[jt][1][0], accz[jt], 0, 0, 0);
            accz[jt]  = __builtin_amdgcn_mfma_f32_16x16x32_bf16(ax1, Wxreg[jt][1][1], accz[jt], 0, 0, 0);
            accxn[jt] = __builtin_amdgcn_mfma_f32_16x16x32_bf16(ax0, Wxreg[jt][2][0], accxn[jt], 0, 0, 0);
            accxn[jt] = __builtin_amdgcn_mfma_f32_16x16x32_bf16(ax1, Wxreg[jt][2][1], accxn[jt], 0, 0, 0);
        }

        // ---- poll A: check-first, reissue-on-miss ----
        {
            int spins = 0;
            while (true) {
                asm volatile("s_waitcnt vmcnt(0)"
                             : "+v"(a0), "+v"(a1), "+v"(a2), "+v"(a3) :: "memory");
                int ok = 1;
                if (pact) ok = chunk_ok(a0) & chunk_ok(a1) & chunk_ok(a2) & chunk_ok(a3);
                if (__all(ok)) break;
                if (++spins > (1 << 18)) break;   // fail loud, never hang
                if (spins >= 64) coh = 1;         // sticky: fast path not working
                if (spins > 8) __builtin_amdgcn_s_sleep(1);
                if (pact) {
                    if (coh) {
                        asm volatile("global_load_dwordx4 %0, %1, off sc0 sc1" : "=v"(a0) : "v"(p));
                        asm volatile("global_load_dwordx4 %0, %1, off sc0 sc1" : "=v"(a1) : "v"(p + 32));
                        asm volatile("global_load_dwordx4 %0, %1, off sc0 sc1" : "=v"(a2) : "v"(p + 64));
                        asm volatile("global_load_dwordx4 %0, %1, off sc0 sc1" : "=v"(a3) : "v"(p + 96));
                    } else {
                        asm volatile("global_load_dwordx4 %0, %1, off sc0" : "=v"(a0) : "v"(p));
                        asm volatile("global_load_dwordx4 %0, %1, off sc0" : "=v"(a1) : "v"(p + 32));
                        asm volatile("global_load_dwordx4 %0, %1, off sc0" : "=v"(a2) : "v"(p + 64));
                        asm volatile("global_load_dwordx4 %0, %1, off sc0" : "=v"(a3) : "v"(p + 96));
                    }
                }
            }
        }

        // ---- issue group B; overlap with group-A MFMAs ----
        if (pact) {
            if (coh) {
                asm volatile("global_load_dwordx4 %0, %1, off sc0 sc1" : "=v"(a4) : "v"(p + 128));
                asm volatile("global_load_dwordx4 %0, %1, off sc0 sc1" : "=v"(a5) : "v"(p + 160));
                asm volatile("global_load_dwordx4 %0, %1, off sc0 sc1" : "=v"(a6) : "v"(p + 192));
                asm volatile("global_load_dwordx4 %0, %1, off sc0 sc1" : "=v"(a7) : "v"(p + 224));
            } else {
                asm volatile("global_load_dwordx4 %0, %1, off sc0" : "=v"(a4) : "v"(p + 128));
                asm volatile("global_load_dwordx4 %0, %1, off sc0" : "=v"(a5) : "v"(p + 160));
                asm volatile("global_load_dwordx4 %0, %1, off sc0" : "=v"(a6) : "v"(p + 192));
                asm volatile("global_load_dwordx4 %0, %1, off sc0" : "=v"(a7) : "v"(p + 224));
            }
        }

#pragma unroll
        for (int jt = 0; jt < 2; jt++) {
            accr[jt]  = __builtin_amdgcn_mfma_f32_16x16x32_bf16(a0, Wreg[jt][0][0], accr[jt], 0, 0, 0);
            accr[jt]  = __builtin_amdgcn_mfma_f32_16x16x32_bf16(a1, Wreg[jt][0][1], accr[jt], 0, 0, 0);
            accr[jt]  = __builtin_amdgcn_mfma_f32_16x16x32_bf16(a2, Wreg[jt][0][2], accr[jt], 0, 0, 0);
            accr[jt]  = __builtin_amdgcn_mfma_f32_16x16x32_bf16(a3, Wreg[jt][0][3], accr[jt], 0, 0, 0);
            accz[jt]  = __builtin_amdgcn_mfma_f32_16x16x32_bf16(a0, Wreg[jt][1][0], accz[jt], 0, 0, 0);
            accz[jt]  = __builtin_amdgcn_mfma_f32_16x16x32_bf16(a1, Wreg[jt][1][1], accz[jt], 0, 0, 0);
            accz[jt]  = __builtin_amdgcn_mfma_f32_16x16x32_bf16(a2, Wreg[jt][1][2], accz[jt], 0, 0, 0);
            accz[jt]  = __builtin_amdgcn_mfma_f32_16x16x32_bf16(a3, Wreg[jt][1][3], accz[jt], 0, 0, 0);
            acchn[jt] = __builtin_amdgcn_mfma_f32_16x16x32_bf16(a0, Wreg[jt][2][0], acchn[jt], 0, 0, 0);
            acchn[jt] = __builtin_amdgcn_mfma_f32_16x16x32_bf16(a1, Wreg[jt][2][1], acchn[jt], 0, 0, 0);
            acchn[jt] = __builtin_amdgcn_mfma_f32_16x16x32_bf16(a2, Wreg[jt][2][2], acchn[jt], 0, 0, 0);
            acchn[jt] = __builtin_amdgcn_mfma_f32_16x16x32_bf16(a3, Wreg[jt][2][3], acchn[jt], 0, 0, 0);
        }

        // ---- wait + check group B; reissue only B on miss ----
        {
            int spins = 0;
            while (true) {
                asm volatile("s_waitcnt vmcnt(0)"
                             : "+v"(a4), "+v"(a5), "+v"(a6), "+v"(a7) :: "memory");
                int ok = 1;
                if (pact) ok = chunk_ok(a4) & chunk_ok(a5) & chunk_ok(a6) & chunk_ok(a7);
                if (__all(ok)) break;
                if (++spins > (1 << 18)) break;
                if (spins >= 64) coh = 1;
                if (spins > 8) __builtin_amdgcn_s_sleep(1);
                if (pact) {
                    if (coh) {
                        asm volatile("global_load_dwordx4 %0, %1, off sc0 sc1" : "=v"(a4) : "v"(p + 128));
                        asm volatile("global_load_dwordx4 %0, %1, off sc0 sc1" : "=v"(a5) : "v"(p + 160));
                        asm volatile("global_load_dwordx4 %0, %1, off sc0 sc1" : "=v"(a6) : "v"(p + 192));
                        asm volatile("global_load_dwordx4 %0, %1, off sc0 sc1" : "=v"(a7) : "v"(p + 224));
                    } else {
                        asm volatile("global_load_dwordx4 %0, %1, off sc0" : "=v"(a4) : "v"(p + 128));
                        asm volatile("global_load_dwordx4 %0, %1, off sc0" : "=v"(a5) : "v"(p + 160));
                        asm volatile("global_load_dwordx4 %0, %1, off sc0" : "=v"(a6) : "v"(p + 192));
                        asm volatile("global_load_dwordx4 %0, %1, off sc0" : "=v"(a7) : "v"(p + 224));
                    }
                }
            }
        }
#pragma unroll
        for (int jt = 0; jt < 2; jt++) {
            accr[jt]  = __builtin_amdgcn_mfma_f32_16x16x32_bf16(a4, Wreg[jt][0][4], accr[jt], 0, 0, 0);
            accr[jt]  = __builtin_amdgcn_mfma_f32_16x16x32_bf16(a5, Wreg[jt][0][5], accr[jt], 0, 0, 0);
            accr[jt]  = __builtin_amdgcn_mfma_f32_16x16x32_bf16(a6, Wreg[jt][0][6], accr[jt], 0, 0, 0);
            accr[jt]  = __builtin_amdgcn_mfma_f32_16x16x32_bf16(a7, Wreg[jt][0][7], accr[jt], 0, 0, 0);
            accz[jt]  = __builtin_amdgcn_mfma_f32_16x16x32_bf16(a4, Wreg[jt][1][4], accz[jt], 0, 0, 0);
            accz[jt]  = __builtin_amdgcn_mfma_f32_16x16x32_bf16(a5, Wreg[jt][1][5], accz[jt], 0, 0, 0);
            accz[jt]  = __builtin_amdgcn_mfma_f32_16x16x32_bf16(a6, Wreg[jt][1][6], accz[jt], 0, 0, 0);
            accz[jt]  = __builtin_amdgcn_mfma_f32_16x16x32_bf16(a7, Wreg[jt][1][7], accz[jt], 0, 0, 0);
            acchn[jt] = __builtin_amdgcn_mfma_f32_16x16x32_bf16(a4, Wreg[jt][2][4], acchn[jt], 0, 0, 0);
            acchn[jt] = __builtin_amdgcn_mfma_f32_16x16x32_bf16(a5, Wreg[jt][2][5], acchn[jt], 0, 0, 0);
            acchn[jt] = __builtin_amdgcn_mfma_f32_16x16x32_bf16(a6, Wreg[jt][2][6], acchn[jt], 0, 0, 0);
            acchn[jt] = __builtin_amdgcn_mfma_f32_16x16x32_bf16(a7, Wreg[jt][2][7], acchn[jt], 0, 0, 0);
        }

        // ---- parity LDS reduce (one barrier per step, round-0 layout) ----
        int par = t & 1;
#pragma unroll
        for (int jt = 0; jt < 2; jt++) {
            red[par][wave][jt * 4 + 0][lane] = accr[jt];
            red[par][wave][jt * 4 + 1][lane] = accz[jt];
            red[par][wave][jt * 4 + 2][lane] = acchn[jt];
            red[par][wave][jt * 4 + 3][lane] = accxn[jt];
        }
        __syncthreads();

        if (act) {
#pragma unroll
            for (int jt = 0; jt < 2; jt++) {
                float sr = 0.f, sz = 0.f, shn = 0.f, sxn = 0.f;
#pragma unroll
                for (int w = 0; w < 4; w++) {
                    sr  += red[par][w][jt * 4 + 0][Lp][reg];
                    sz  += red[par][w][jt * 4 + 1][Lp][reg];
                    shn += red[par][w][jt * 4 + 2][Lp][reg];
                    sxn += red[par][w][jt * 4 + 3][Lp][reg];
                }
                float r = 1.0f / (1.0f + __expf(-(sr + bhv[jt][0])));
                float z = 1.0f / (1.0f + __expf(-(sz + bhv[jt][1])));
                float n = tanhf(sxn + r * (shn + bhv[jt][2]));
                float hnew = (1.0f - z) * n + z * hreg[jt];
                hreg[jt] = hnew;

                unsigned short hbv = f2bf(hnew);
                if (hbv == 0xAAAAu) hbv = 0xAAABu;   // never store the sentinel

                int j = jbase + jt * 16 + jcol;
                unsigned short* hp = hist_t1 + (size_t)b * H_ + j;
                unsigned hv32 = hbv;
                // fast copy: local XCD L2 (for same-XCD sc0 polls)
                asm volatile("global_store_short %0, %1, off sc0"
                             :: "v"(hp), "v"(hv32) : "memory");
                // safety copy, SAME address SAME value: L3 (for sticky sc0sc1 polls)
                asm volatile("global_store_short %0, %1, off sc0 sc1"
                             :: "v"(hp), "v"(hv32) : "memory");
                yB[((size_t)b * L_ + t) * H_ + j] = hbv;   // consumed after kernel end
            }
        }
    }
}

// ---- phase 3: logits[m][v] = y[m] @ Wout + bout   (M=16384, K=1024, N=256) ----
__global__ __launch_bounds__(256) void out_gemm(const unsigned short* __restrict__ yB,
                                                const unsigned short* __restrict__ WoutT,
                                                const float* __restrict__ bout,
                                                float* __restrict__ out) {
    int ntile = blockIdx.x;
    int mtile = blockIdx.y;
    int wave = threadIdx.x >> 6, lane = threadIdx.x & 63;
    int l16 = lane & 15, q = lane >> 4;

    int m = mtile * 64 + wave * 16 + l16;
    const bf16x8* Arow = (const bf16x8*)(yB + (size_t)m * H_);
    int n0 = ntile * 64;

    f32x4 acc[4] = {};
    for (int k0 = 0; k0 < H_; k0 += 32) {
        bf16x8 a = Arow[(k0 >> 3) + q];
#pragma unroll
        for (int j = 0; j < 4; j++) {
            const bf16x8* Brow = (const bf16x8*)(WoutT + (size_t)(n0 + j*16 + l16) * H_);
            bf16x8 b = Brow[(k0 >> 3) + q];
            acc[j] = __builtin_amdgcn_mfma_f32_16x16x32_bf16(a, b, acc[j], 0, 0, 0);
        }
    }
    int mrow = mtile * 64 + wave * 16 + q * 4;
#pragma unroll
    for (int j = 0; j < 4; j++) {
        int n = n0 + j * 16 + l16;
        float bias = bout[n];
#pragma unroll
        for (int r = 0; r < 4; r++)
            out[(size_t)(mrow + r) * V_ + n] = acc[j][r] + bias;
    }
}

extern "C" void kernel_launch(void* const* d_in, const int* in_sizes, int n_in,
                              void* d_out, int out_size, void* d_ws, size_t ws_size,
                              hipStream_t stream) {
    const int*   tokens = (const int*)  d_in[0];
    const float* emb    = (const float*)d_in[1];
    const float* Wi     = (const float*)d_in[2];
    const float* Wh     = (const float*)d_in[3];
    const float* bh     = (const float*)d_in[4];
    const float* Wout   = (const float*)d_in[5];
    const float* bout   = (const float*)d_in[6];
    float* out = (float*)d_out;

    char* ws = (char*)d_ws;
    size_t off = 0;
    auto alloc = [&](size_t bytes) -> void* {
        void* p = ws + off;
        off += (bytes + 255) & ~(size_t)255;
        return p;
    };
    unsigned short* WhT   = (unsigned short*)alloc((size_t)H3 * H_ * 2);   // 6 MB
    unsigned short* WiT   = (unsigned short*)alloc((size_t)H3 * E_ * 2);   // 1.5 MB
    unsigned short* WoutT = (unsigned short*)alloc((size_t)V_ * H_ * 2);   // 0.5 MB
    unsigned short* embB  = (unsigned short*)alloc((size_t)V_ * E_ * 2);   // 128 KB
    unsigned short* yB    = (unsigned short*)alloc((size_t)B_ * L_ * H_ * 2); // 32 MB
    unsigned short* hist  = (unsigned short*)alloc((size_t)(L_ + 1) * B_ * H_ * 2); // 33.7 MB
    int*            ctl   = (int*)alloc(64 * sizeof(int));

    prep_all<<<12544, 256, 0, stream>>>(Wh, Wi, Wout, emb, WhT, WiT, WoutT,
                                        embB, hist, (uint4*)(hist + (size_t)B_ * H_), ctl);

    {
        unsigned short* ah = hist;
        const unsigned short* aW = WhT; const unsigned short* aWx = WiT;
        const unsigned short* ae = embB; const int* at = tokens;
        const float* ab = bh; unsigned short* ay = yB;
        int* ac = ctl;
        void* args[] = {&ah, &aW, &aWx, &ae, &at, &ab, &ay, &ac};
        hipError_t err = hipLaunchCooperativeKernel((void*)gru_persistent,
                                                    dim3(256), dim3(256), args, 0, stream);
        if (err != hipSuccess) {
            // fallback: plain launch; 256 blocks at 1 block/CU co-reside on 256 CUs,
            // and all spins are bounded (fail loud via absmax, not hang)
            gru_persistent<<<dim3(256), dim3(256), 0, stream>>>(
                ah, aW, aWx, ae, at, ab, ay, ac);
        }
    }

    out_gemm<<<dim3(4, 256), 256, 0, stream>>>(yB, WoutT, bout, out);
}

// Round 5
// 1500.167 us; speedup vs baseline: 1.1195x; 1.1195x over previous
//
#include <hip/hip_runtime.h>
#include <cstdint>
#include <math.h>

#define B_  64
#define L_  256
#define V_  256
#define E_  256
#define H_  1024
#define H3  3072

typedef __bf16 bf16x8 __attribute__((ext_vector_type(8)));
typedef float  f32x4  __attribute__((ext_vector_type(4)));

__device__ __forceinline__ unsigned short f2bf(float f) {
    union { float f; unsigned u; } v; v.f = f;
    unsigned r = v.u + 0x7fffu + ((v.u >> 16) & 1u);   // round-to-nearest-even
    return (unsigned short)(r >> 16);
}

// ok iff NO 16-bit half of any dword equals the 0xAAAA poison sentinel
__device__ __forceinline__ int chunk_ok(bf16x8 v) {
    union { bf16x8 b; unsigned u[4]; } cv; cv.b = v;
    int ok = 1;
#pragma unroll
    for (int i = 0; i < 4; i++) {
        unsigned x = cv.u[i] ^ 0xAAAAAAAAu;
        ok &= (int)((x & 0xFFFFu) != 0u) & (int)((x >> 16) != 0u);
    }
    return ok;
}

__device__ __forceinline__ float sigmoid_f(float x) {
    return __builtin_amdgcn_rcpf(1.0f + __expf(-x));
}
__device__ __forceinline__ float tanh_f(float x) {
    // tanh(x) = 1 - 2/(e^{2x}+1); saturates correctly at +-inf
    return 1.0f - 2.0f * __builtin_amdgcn_rcpf(1.0f + __expf(2.0f * x));
}

// ---- single prep kernel: 3 transposes + emb convert + h0 zero + hist poison ----
// grid regions: [0,3072) WhT tiles; [3072,3840) WiT; [3840,4096) WoutT;
// [4096,4352) embB+h0; [4352,12544) poison slots 1..256.
__global__ __launch_bounds__(256) void prep_all(
        const float* __restrict__ Wh, const float* __restrict__ Wi,
        const float* __restrict__ Wout, const float* __restrict__ emb,
        unsigned short* __restrict__ WhT, unsigned short* __restrict__ WiT,
        unsigned short* __restrict__ WoutT, unsigned short* __restrict__ embB,
        unsigned short* __restrict__ h0b, uint4* __restrict__ poison) {
    __shared__ unsigned short tile[32][34];
    int bid = blockIdx.x;
    const float* src; unsigned short* dst; int rows, cols, nt, kt;
    if (bid < 3072)      { src = Wh;   dst = WhT;   rows = H_; cols = H3; nt = bid % 96; kt = bid / 96; }
    else if (bid < 3840) { int b = bid - 3072; src = Wi;   dst = WiT;   rows = E_; cols = H3; nt = b % 96; kt = b / 96; }
    else if (bid < 4096) { int b = bid - 3840; src = Wout; dst = WoutT; rows = H_; cols = V_; nt = b % 8;  kt = b / 8; }
    else if (bid < 4352) {
        int idx = (bid - 4096) * 256 + threadIdx.x;   // 65536 = V*E = B*H
        embB[idx] = f2bf(emb[idx]);
        h0b[idx]  = 0;
        return;
    } else {
        size_t T = (size_t)(bid - 4352) * 256 + threadIdx.x;   // 2M uint4 = 33.55 MB
        uint4 v; v.x = v.y = v.z = v.w = 0xAAAAAAAAu;
        poison[T] = v;
        return;
    }
    int n0 = nt * 32, k0 = kt * 32;
    int tx = threadIdx.x & 31, ty = threadIdx.x >> 5;
#pragma unroll
    for (int j = 0; j < 32; j += 8)
        tile[tx][ty + j] = f2bf(src[(size_t)(k0 + ty + j) * cols + (n0 + tx)]);
    __syncthreads();
#pragma unroll
    for (int j = 0; j < 32; j += 8)
        dst[(size_t)(n0 + ty + j) * rows + (k0 + tx)] = tile[ty + j][tx];
}

// ---- phase 2: persistent GRU; round-0 topology exactly, minus exposed latency:
//      all 8 poll loads issued at step top (tok/emb/xw in their shadow),
//      combined first check (common case: 1 RTT total), round-0 A/B re-poll
//      fallback on miss, rcp-based activations. ----
__global__ __launch_bounds__(256, 1) void gru_persistent(
        unsigned short* __restrict__ hist,        // [257][B][H], slot0=0, rest poisoned
        const unsigned short* __restrict__ WhT,   // [3H][H]
        const unsigned short* __restrict__ WiT,   // [3H][E]
        const unsigned short* __restrict__ embB,  // [V][E]
        const int* __restrict__ tokens,           // [B][L]
        const float* __restrict__ bh,
        unsigned short* __restrict__ yB) {        // [B][L][H]
    __shared__ f32x4 red[2][4][6][64];            // [parity][wave][slot][lane]

    int bid = blockIdx.x;
    int btile = bid & 3;
    int jtile = bid >> 2;
    int wave = threadIdx.x >> 6, lane = threadIdx.x & 63;
    int l16 = lane & 15, q = lane >> 4;
    int b0 = btile * 16, j0 = jtile * 16;
    int kbase = wave * 256;

    // ---- pin Wh fragments (96 VGPR/lane) ----
    bf16x8 Wreg[3][8];
#pragma unroll
    for (int g = 0; g < 3; g++) {
        const bf16x8* Brow = (const bf16x8*)(WhT + (size_t)(g * H_ + j0 + l16) * H_);
#pragma unroll
        for (int kk = 0; kk < 8; kk++) {
            Wreg[g][kk] = Brow[(kbase >> 3) + kk * 4 + q];
            asm volatile("" : "+v"(Wreg[g][kk]));
        }
    }
    // ---- pin Wi fragments (24 VGPR/lane) ----
    bf16x8 Wxreg[3][2];
#pragma unroll
    for (int g = 0; g < 3; g++) {
        const bf16x8* Bx = (const bf16x8*)(WiT + (size_t)(g * H_ + j0 + l16) * E_);
#pragma unroll
        for (int c = 0; c < 2; c++) {
            Wxreg[g][c] = Bx[wave * 8 + c * 4 + q];
            asm volatile("" : "+v"(Wxreg[g][c]));
        }
    }

    // ---- per-thread gate mapping / biases / fp32 state ----
    int Lp  = threadIdx.x & 63;
    int reg = threadIdx.x >> 6;
    int b_local = (Lp >> 4) * 4 + reg;
    int j_local = Lp & 15;
    int b = b0 + b_local, jg = j0 + j_local;
    float bhr = bh[jg];
    float bhz = bh[H_ + jg];
    float bhn = bh[2 * H_ + jg];
    asm volatile("" : "+v"(bhr), "+v"(bhz), "+v"(bhn));
    float hreg = 0.0f;

    const int tokrow = (b0 + l16) * L_;

    for (int t = 0; t < L_; t++) {
        const unsigned short* hist_t  = hist + (size_t)t * (B_ * H_);
        unsigned short*       hist_t1 = hist + (size_t)(t + 1) * (B_ * H_);
        const unsigned short* p = hist_t + (size_t)(b0 + l16) * H_ + kbase + q * 8;

        bf16x8 a0, a1, a2, a3, a4, a5, a6, a7;
        // ---- issue ALL 8 poll loads first: the L3 RTT clock starts now ----
        asm volatile("global_load_dwordx4 %0, %1, off sc0 sc1" : "=v"(a0) : "v"(p));
        asm volatile("global_load_dwordx4 %0, %1, off sc0 sc1" : "=v"(a1) : "v"(p + 32));
        asm volatile("global_load_dwordx4 %0, %1, off sc0 sc1" : "=v"(a2) : "v"(p + 64));
        asm volatile("global_load_dwordx4 %0, %1, off sc0 sc1" : "=v"(a3) : "v"(p + 96));
        asm volatile("global_load_dwordx4 %0, %1, off sc0 sc1" : "=v"(a4) : "v"(p + 128));
        asm volatile("global_load_dwordx4 %0, %1, off sc0 sc1" : "=v"(a5) : "v"(p + 160));
        asm volatile("global_load_dwordx4 %0, %1, off sc0 sc1" : "=v"(a6) : "v"(p + 192));
        asm volatile("global_load_dwordx4 %0, %1, off sc0 sc1" : "=v"(a7) : "v"(p + 224));

        // ---- tok + emb loads and xw MFMAs run in the poll shadow ----
        int tok = tokens[tokrow + t];
        const bf16x8* Ax = (const bf16x8*)(embB + (size_t)tok * E_);
        bf16x8 ax0 = Ax[wave * 8 + q];
        bf16x8 ax1 = Ax[wave * 8 + 4 + q];
        f32x4 xacc[3] = {};
#pragma unroll
        for (int g = 0; g < 3; g++) {
            xacc[g] = __builtin_amdgcn_mfma_f32_16x16x32_bf16(ax0, Wxreg[g][0], xacc[g], 0, 0, 0);
            xacc[g] = __builtin_amdgcn_mfma_f32_16x16x32_bf16(ax1, Wxreg[g][1], xacc[g], 0, 0, 0);
        }

        // ---- combined first check (common case: everything already stored) ----
        asm volatile("s_waitcnt vmcnt(0)"
                     : "+v"(a0), "+v"(a1), "+v"(a2), "+v"(a3),
                       "+v"(a4), "+v"(a5), "+v"(a6), "+v"(a7) :: "memory");
        int okA = chunk_ok(a0) & chunk_ok(a1) & chunk_ok(a2) & chunk_ok(a3);
        int okB = chunk_ok(a4) & chunk_ok(a5) & chunk_ok(a6) & chunk_ok(a7);
        if (!__all(okA & okB)) {
            // ---- fallback: round-0 semantics, re-issue only the failed group ----
            int spins = 0;
            while (!__all(okA)) {
                if (++spins > (1 << 18)) break;   // fail loud, never hang
                if (spins > 64) __builtin_amdgcn_s_sleep(1);
                asm volatile("global_load_dwordx4 %0, %1, off sc0 sc1" : "=v"(a0) : "v"(p));
                asm volatile("global_load_dwordx4 %0, %1, off sc0 sc1" : "=v"(a1) : "v"(p + 32));
                asm volatile("global_load_dwordx4 %0, %1, off sc0 sc1" : "=v"(a2) : "v"(p + 64));
                asm volatile("global_load_dwordx4 %0, %1, off sc0 sc1" : "=v"(a3) : "v"(p + 96));
                asm volatile("s_waitcnt vmcnt(0)"
                             : "+v"(a0), "+v"(a1), "+v"(a2), "+v"(a3) :: "memory");
                okA = chunk_ok(a0) & chunk_ok(a1) & chunk_ok(a2) & chunk_ok(a3);
            }
            spins = 0;
            while (!__all(okB)) {
                if (++spins > (1 << 18)) break;
                if (spins > 64) __builtin_amdgcn_s_sleep(1);
                asm volatile("global_load_dwordx4 %0, %1, off sc0 sc1" : "=v"(a4) : "v"(p + 128));
                asm volatile("global_load_dwordx4 %0, %1, off sc0 sc1" : "=v"(a5) : "v"(p + 160));
                asm volatile("global_load_dwordx4 %0, %1, off sc0 sc1" : "=v"(a6) : "v"(p + 192));
                asm volatile("global_load_dwordx4 %0, %1, off sc0 sc1" : "=v"(a7) : "v"(p + 224));
                asm volatile("s_waitcnt vmcnt(0)"
                             : "+v"(a4), "+v"(a5), "+v"(a6), "+v"(a7) :: "memory");
                okB = chunk_ok(a4) & chunk_ok(a5) & chunk_ok(a6) & chunk_ok(a7);
            }
        }

        // ---- 24 Wh MFMAs (all operands valid) ----
        f32x4 acc[3] = {};
#pragma unroll
        for (int g = 0; g < 3; g++) {
            acc[g] = __builtin_amdgcn_mfma_f32_16x16x32_bf16(a0, Wreg[g][0], acc[g], 0, 0, 0);
            acc[g] = __builtin_amdgcn_mfma_f32_16x16x32_bf16(a1, Wreg[g][1], acc[g], 0, 0, 0);
            acc[g] = __builtin_amdgcn_mfma_f32_16x16x32_bf16(a2, Wreg[g][2], acc[g], 0, 0, 0);
            acc[g] = __builtin_amdgcn_mfma_f32_16x16x32_bf16(a3, Wreg[g][3], acc[g], 0, 0, 0);
            acc[g] = __builtin_amdgcn_mfma_f32_16x16x32_bf16(a4, Wreg[g][4], acc[g], 0, 0, 0);
            acc[g] = __builtin_amdgcn_mfma_f32_16x16x32_bf16(a5, Wreg[g][5], acc[g], 0, 0, 0);
            acc[g] = __builtin_amdgcn_mfma_f32_16x16x32_bf16(a6, Wreg[g][6], acc[g], 0, 0, 0);
            acc[g] = __builtin_amdgcn_mfma_f32_16x16x32_bf16(a7, Wreg[g][7], acc[g], 0, 0, 0);
        }

        // ---- parity LDS reduce (round-0 zero-conflict layout, one barrier) ----
        int par = t & 1;
#pragma unroll
        for (int g = 0; g < 3; g++) {
            red[par][wave][g][lane]     = acc[g];
            red[par][wave][3 + g][lane] = xacc[g];
        }
        __syncthreads();

        float gh0 = red[par][0][0][Lp][reg] + red[par][1][0][Lp][reg] + red[par][2][0][Lp][reg] + red[par][3][0][Lp][reg];
        float gh1 = red[par][0][1][Lp][reg] + red[par][1][1][Lp][reg] + red[par][2][1][Lp][reg] + red[par][3][1][Lp][reg];
        float gh2 = red[par][0][2][Lp][reg] + red[par][1][2][Lp][reg] + red[par][2][2][Lp][reg] + red[par][3][2][Lp][reg];
        float xr  = red[par][0][3][Lp][reg] + red[par][1][3][Lp][reg] + red[par][2][3][Lp][reg] + red[par][3][3][Lp][reg];
        float xz  = red[par][0][4][Lp][reg] + red[par][1][4][Lp][reg] + red[par][2][4][Lp][reg] + red[par][3][4][Lp][reg];
        float xn  = red[par][0][5][Lp][reg] + red[par][1][5][Lp][reg] + red[par][2][5][Lp][reg] + red[par][3][5][Lp][reg];

        float r = sigmoid_f(xr + gh0 + bhr);
        float z = sigmoid_f(xz + gh1 + bhz);
        float n = tanh_f(xn + r * (gh2 + bhn));
        float hnew = n + z * (hreg - n);
        hreg = hnew;

        unsigned short hbv = f2bf(hnew);
        if (hbv == 0xAAAAu) hbv = 0xAAABu;   // never store the sentinel

        {
            unsigned short* hp = hist_t1 + (size_t)b * H_ + jg;
            unsigned hv32 = hbv;
            asm volatile("global_store_short %0, %1, off sc0 sc1"
                         :: "v"(hp), "v"(hv32) : "memory");
        }
        yB[((size_t)b * L_ + t) * H_ + jg] = hbv;   // cached; consumed after kernel end
    }
}

// ---- phase 3: logits[m][v] = y[m] @ Wout + bout   (M=16384, K=1024, N=256) ----
__global__ __launch_bounds__(256) void out_gemm(const unsigned short* __restrict__ yB,
                                                const unsigned short* __restrict__ WoutT,
                                                const float* __restrict__ bout,
                                                float* __restrict__ out) {
    int ntile = blockIdx.x;
    int mtile = blockIdx.y;
    int wave = threadIdx.x >> 6, lane = threadIdx.x & 63;
    int l16 = lane & 15, q = lane >> 4;

    int m = mtile * 64 + wave * 16 + l16;
    const bf16x8* Arow = (const bf16x8*)(yB + (size_t)m * H_);
    int n0 = ntile * 64;

    f32x4 acc[4] = {};
    for (int k0 = 0; k0 < H_; k0 += 32) {
        bf16x8 a = Arow[(k0 >> 3) + q];
#pragma unroll
        for (int j = 0; j < 4; j++) {
            const bf16x8* Brow = (const bf16x8*)(WoutT + (size_t)(n0 + j*16 + l16) * H_);
            bf16x8 b = Brow[(k0 >> 3) + q];
            acc[j] = __builtin_amdgcn_mfma_f32_16x16x32_bf16(a, b, acc[j], 0, 0, 0);
        }
    }
    int mrow = mtile * 64 + wave * 16 + q * 4;
#pragma unroll
    for (int j = 0; j < 4; j++) {
        int n = n0 + j * 16 + l16;
        float bias = bout[n];
#pragma unroll
        for (int r = 0; r < 4; r++)
            out[(size_t)(mrow + r) * V_ + n] = acc[j][r] + bias;
    }
}

extern "C" void kernel_launch(void* const* d_in, const int* in_sizes, int n_in,
                              void* d_out, int out_size, void* d_ws, size_t ws_size,
                              hipStream_t stream) {
    const int*   tokens = (const int*)  d_in[0];
    const float* emb    = (const float*)d_in[1];
    const float* Wi     = (const float*)d_in[2];
    const float* Wh     = (const float*)d_in[3];
    const float* bh     = (const float*)d_in[4];
    const float* Wout   = (const float*)d_in[5];
    const float* bout   = (const float*)d_in[6];
    float* out = (float*)d_out;

    char* ws = (char*)d_ws;
    size_t off = 0;
    auto alloc = [&](size_t bytes) -> void* {
        void* p = ws + off;
        off += (bytes + 255) & ~(size_t)255;
        return p;
    };
    unsigned short* WhT   = (unsigned short*)alloc((size_t)H3 * H_ * 2);   // 6 MB
    unsigned short* WiT   = (unsigned short*)alloc((size_t)H3 * E_ * 2);   // 1.5 MB
    unsigned short* WoutT = (unsigned short*)alloc((size_t)V_ * H_ * 2);   // 0.5 MB
    unsigned short* embB  = (unsigned short*)alloc((size_t)V_ * E_ * 2);   // 128 KB
    unsigned short* yB    = (unsigned short*)alloc((size_t)B_ * L_ * H_ * 2); // 32 MB
    unsigned short* hist  = (unsigned short*)alloc((size_t)(L_ + 1) * B_ * H_ * 2); // 33.7 MB

    prep_all<<<12544, 256, 0, stream>>>(Wh, Wi, Wout, emb, WhT, WiT, WoutT,
                                        embB, hist, (uint4*)(hist + (size_t)B_ * H_));

    {
        unsigned short* ah = hist;
        const unsigned short* aW = WhT; const unsigned short* aWx = WiT;
        const unsigned short* ae = embB; const int* at = tokens;
        const float* ab = bh; unsigned short* ay = yB;
        void* args[] = {&ah, &aW, &aWx, &ae, &at, &ab, &ay};
        hipError_t err = hipLaunchCooperativeKernel((void*)gru_persistent,
                                                    dim3(256), dim3(256), args, 0, stream);
        if (err != hipSuccess) {
            // fallback: plain launch; 256 blocks at 1 block/CU co-reside on 256 CUs,
            // and all spins are bounded (fail loud via absmax, not hang)
            gru_persistent<<<dim3(256), dim3(256), 0, stream>>>(
                ah, aW, aWx, ae, at, ab, ay);
        }
    }

    out_gemm<<<dim3(4, 256), 256, 0, stream>>>(yB, WoutT, bout, out);
}

// Round 6
// 1396.358 us; speedup vs baseline: 1.2027x; 1.0743x over previous
//
#include <hip/hip_runtime.h>
#include <cstdint>
#include <math.h>

#define B_  64
#define L_  256
#define V_  256
#define E_  256
#define H_  1024
#define H3  3072

typedef __bf16 bf16x8 __attribute__((ext_vector_type(8)));
typedef float  f32x4  __attribute__((ext_vector_type(4)));

__device__ __forceinline__ unsigned short f2bf(float f) {
    union { float f; unsigned u; } v; v.f = f;
    unsigned r = v.u + 0x7fffu + ((v.u >> 16) & 1u);   // round-to-nearest-even
    return (unsigned short)(r >> 16);
}

// ok iff NO 16-bit half of any dword equals the 0xAAAA poison sentinel
__device__ __forceinline__ int chunk_ok(bf16x8 v) {
    union { bf16x8 b; unsigned u[4]; } cv; cv.b = v;
    int ok = 1;
#pragma unroll
    for (int i = 0; i < 4; i++) {
        unsigned x = cv.u[i] ^ 0xAAAAAAAAu;
        ok &= (int)((x & 0xFFFFu) != 0u) & (int)((x >> 16) != 0u);
    }
    return ok;
}

__device__ __forceinline__ float sigmoid_f(float x) {
    return __builtin_amdgcn_rcpf(1.0f + __expf(-x));
}
__device__ __forceinline__ float tanh_f(float x) {
    // tanh(x) = 1 - 2/(e^{2x}+1); saturates correctly at +-inf
    return 1.0f - 2.0f * __builtin_amdgcn_rcpf(1.0f + __expf(2.0f * x));
}

// ---- single prep kernel: 3 transposes + emb convert + h0 zero + hist poison ----
// grid regions: [0,3072) WhT tiles; [3072,3840) WiT; [3840,4096) WoutT;
// [4096,4352) embB+h0; [4352,12544) poison slots 1..256.
__global__ __launch_bounds__(256) void prep_all(
        const float* __restrict__ Wh, const float* __restrict__ Wi,
        const float* __restrict__ Wout, const float* __restrict__ emb,
        unsigned short* __restrict__ WhT, unsigned short* __restrict__ WiT,
        unsigned short* __restrict__ WoutT, unsigned short* __restrict__ embB,
        unsigned short* __restrict__ h0b, uint4* __restrict__ poison) {
    __shared__ unsigned short tile[32][34];
    int bid = blockIdx.x;
    const float* src; unsigned short* dst; int rows, cols, nt, kt;
    if (bid < 3072)      { src = Wh;   dst = WhT;   rows = H_; cols = H3; nt = bid % 96; kt = bid / 96; }
    else if (bid < 3840) { int b = bid - 3072; src = Wi;   dst = WiT;   rows = E_; cols = H3; nt = b % 96; kt = b / 96; }
    else if (bid < 4096) { int b = bid - 3840; src = Wout; dst = WoutT; rows = H_; cols = V_; nt = b % 8;  kt = b / 8; }
    else if (bid < 4352) {
        int idx = (bid - 4096) * 256 + threadIdx.x;   // 65536 = V*E = B*H
        embB[idx] = f2bf(emb[idx]);
        h0b[idx]  = 0;
        return;
    } else {
        size_t T = (size_t)(bid - 4352) * 256 + threadIdx.x;   // 2M uint4 = 33.55 MB
        uint4 v; v.x = v.y = v.z = v.w = 0xAAAAAAAAu;
        poison[T] = v;
        return;
    }
    int n0 = nt * 32, k0 = kt * 32;
    int tx = threadIdx.x & 31, ty = threadIdx.x >> 5;
#pragma unroll
    for (int j = 0; j < 32; j += 8)
        tile[tx][ty + j] = f2bf(src[(size_t)(k0 + ty + j) * cols + (n0 + tx)]);
    __syncthreads();
#pragma unroll
    for (int j = 0; j < 32; j += 8)
        dst[(size_t)(n0 + ty + j) * rows + (k0 + tx)] = tile[ty + j][tx];
}

// ---- phase 2: persistent GRU; round-0 structure and poll semantics exactly.
//      Only deltas: (1) first A-group load issue hoisted above tok/emb/xw
//      (check-first loop; per-miss behavior identical: sleep -> reissue ->
//      wait -> check); (2) rcp-based activations in the epilogue. ----
__global__ __launch_bounds__(256, 1) void gru_persistent(
        unsigned short* __restrict__ hist,        // [257][B][H], slot0=0, rest poisoned
        const unsigned short* __restrict__ WhT,   // [3H][H]
        const unsigned short* __restrict__ WiT,   // [3H][E]
        const unsigned short* __restrict__ embB,  // [V][E]
        const int* __restrict__ tokens,           // [B][L]
        const float* __restrict__ bh,
        unsigned short* __restrict__ yB) {        // [B][L][H]
    __shared__ f32x4 red[2][4][6][64];            // [parity][wave][slot][lane]

    int bid = blockIdx.x;
    int btile = bid & 3;
    int jtile = bid >> 2;
    int wave = threadIdx.x >> 6, lane = threadIdx.x & 63;
    int l16 = lane & 15, q = lane >> 4;
    int b0 = btile * 16, j0 = jtile * 16;
    int kbase = wave * 256;

    // ---- pin Wh fragments (96 VGPR/lane) ----
    bf16x8 Wreg[3][8];
#pragma unroll
    for (int g = 0; g < 3; g++) {
        const bf16x8* Brow = (const bf16x8*)(WhT + (size_t)(g * H_ + j0 + l16) * H_);
#pragma unroll
        for (int kk = 0; kk < 8; kk++) {
            Wreg[g][kk] = Brow[(kbase >> 3) + kk * 4 + q];
            asm volatile("" : "+v"(Wreg[g][kk]));
        }
    }
    // ---- pin Wi fragments (24 VGPR/lane) ----
    bf16x8 Wxreg[3][2];
#pragma unroll
    for (int g = 0; g < 3; g++) {
        const bf16x8* Bx = (const bf16x8*)(WiT + (size_t)(g * H_ + j0 + l16) * E_);
#pragma unroll
        for (int c = 0; c < 2; c++) {
            Wxreg[g][c] = Bx[wave * 8 + c * 4 + q];
            asm volatile("" : "+v"(Wxreg[g][c]));
        }
    }

    // ---- per-thread gate mapping / biases / fp32 state ----
    int Lp  = threadIdx.x & 63;
    int reg = threadIdx.x >> 6;
    int b_local = (Lp >> 4) * 4 + reg;
    int j_local = Lp & 15;
    int b = b0 + b_local, jg = j0 + j_local;
    float bhr = bh[jg];
    float bhz = bh[H_ + jg];
    float bhn = bh[2 * H_ + jg];
    asm volatile("" : "+v"(bhr), "+v"(bhz), "+v"(bhn));
    float hreg = 0.0f;

    const int tokrow = (b0 + l16) * L_;

    for (int t = 0; t < L_; t++) {
        const unsigned short* hist_t  = hist + (size_t)t * (B_ * H_);
        unsigned short*       hist_t1 = hist + (size_t)(t + 1) * (B_ * H_);
        const unsigned short* p = hist_t + (size_t)(b0 + l16) * H_ + kbase + q * 8;

        bf16x8 a0, a1, a2, a3, a4, a5, a6, a7;
        // ---- issue group A NOW: the L3 RTT clock starts before the xw chain ----
        asm volatile("global_load_dwordx4 %0, %1, off sc0 sc1" : "=v"(a0) : "v"(p));
        asm volatile("global_load_dwordx4 %0, %1, off sc0 sc1" : "=v"(a1) : "v"(p + 32));
        asm volatile("global_load_dwordx4 %0, %1, off sc0 sc1" : "=v"(a2) : "v"(p + 64));
        asm volatile("global_load_dwordx4 %0, %1, off sc0 sc1" : "=v"(a3) : "v"(p + 96));

        // ---- xw partials (h-independent; run in group-A's shadow) ----
        int tok = tokens[tokrow + t];
        const bf16x8* Ax = (const bf16x8*)(embB + (size_t)tok * E_);
        bf16x8 ax0 = Ax[wave * 8 + q];
        bf16x8 ax1 = Ax[wave * 8 + 4 + q];
        f32x4 xacc[3] = {};
#pragma unroll
        for (int g = 0; g < 3; g++) {
            xacc[g] = __builtin_amdgcn_mfma_f32_16x16x32_bf16(ax0, Wxreg[g][0], xacc[g], 0, 0, 0);
            xacc[g] = __builtin_amdgcn_mfma_f32_16x16x32_bf16(ax1, Wxreg[g][1], xacc[g], 0, 0, 0);
        }

        // ---- poll group A (check-first; per-miss = sleep, reissue, wait) ----
        {
            int spins = 0;
            while (true) {
                asm volatile("s_waitcnt vmcnt(0)"
                             : "+v"(a0), "+v"(a1), "+v"(a2), "+v"(a3) :: "memory");
                int ok = chunk_ok(a0) & chunk_ok(a1) & chunk_ok(a2) & chunk_ok(a3);
                if (__all(ok)) break;
                if (++spins > (1 << 18)) break;   // fail loud, never hang
                __builtin_amdgcn_s_sleep(1);
                asm volatile("global_load_dwordx4 %0, %1, off sc0 sc1" : "=v"(a0) : "v"(p));
                asm volatile("global_load_dwordx4 %0, %1, off sc0 sc1" : "=v"(a1) : "v"(p + 32));
                asm volatile("global_load_dwordx4 %0, %1, off sc0 sc1" : "=v"(a2) : "v"(p + 64));
                asm volatile("global_load_dwordx4 %0, %1, off sc0 sc1" : "=v"(a3) : "v"(p + 96));
            }
        }
        // ---- issue group B loads; overlap with group-A MFMAs ----
        asm volatile("global_load_dwordx4 %0, %1, off sc0 sc1" : "=v"(a4) : "v"(p + 128));
        asm volatile("global_load_dwordx4 %0, %1, off sc0 sc1" : "=v"(a5) : "v"(p + 160));
        asm volatile("global_load_dwordx4 %0, %1, off sc0 sc1" : "=v"(a6) : "v"(p + 192));
        asm volatile("global_load_dwordx4 %0, %1, off sc0 sc1" : "=v"(a7) : "v"(p + 224));

        f32x4 acc[3] = {};
#pragma unroll
        for (int g = 0; g < 3; g++) {
            acc[g] = __builtin_amdgcn_mfma_f32_16x16x32_bf16(a0, Wreg[g][0], acc[g], 0, 0, 0);
            acc[g] = __builtin_amdgcn_mfma_f32_16x16x32_bf16(a1, Wreg[g][1], acc[g], 0, 0, 0);
            acc[g] = __builtin_amdgcn_mfma_f32_16x16x32_bf16(a2, Wreg[g][2], acc[g], 0, 0, 0);
            acc[g] = __builtin_amdgcn_mfma_f32_16x16x32_bf16(a3, Wreg[g][3], acc[g], 0, 0, 0);
        }

        // ---- wait + check group B; retry only B on miss ----
        asm volatile("s_waitcnt vmcnt(0)"
                     : "+v"(a4), "+v"(a5), "+v"(a6), "+v"(a7) :: "memory");
        {
            int ok = chunk_ok(a4) & chunk_ok(a5) & chunk_ok(a6) & chunk_ok(a7);
            if (!__all(ok)) {
                int spins = 0;
                while (true) {
                    __builtin_amdgcn_s_sleep(1);
                    asm volatile("global_load_dwordx4 %0, %1, off sc0 sc1" : "=v"(a4) : "v"(p + 128));
                    asm volatile("global_load_dwordx4 %0, %1, off sc0 sc1" : "=v"(a5) : "v"(p + 160));
                    asm volatile("global_load_dwordx4 %0, %1, off sc0 sc1" : "=v"(a6) : "v"(p + 192));
                    asm volatile("global_load_dwordx4 %0, %1, off sc0 sc1" : "=v"(a7) : "v"(p + 224));
                    asm volatile("s_waitcnt vmcnt(0)"
                                 : "+v"(a4), "+v"(a5), "+v"(a6), "+v"(a7) :: "memory");
                    int ok2 = chunk_ok(a4) & chunk_ok(a5) & chunk_ok(a6) & chunk_ok(a7);
                    if (__all(ok2)) break;
                    if (++spins > (1 << 18)) break;
                }
            }
        }
#pragma unroll
        for (int g = 0; g < 3; g++) {
            acc[g] = __builtin_amdgcn_mfma_f32_16x16x32_bf16(a4, Wreg[g][4], acc[g], 0, 0, 0);
            acc[g] = __builtin_amdgcn_mfma_f32_16x16x32_bf16(a5, Wreg[g][5], acc[g], 0, 0, 0);
            acc[g] = __builtin_amdgcn_mfma_f32_16x16x32_bf16(a6, Wreg[g][6], acc[g], 0, 0, 0);
            acc[g] = __builtin_amdgcn_mfma_f32_16x16x32_bf16(a7, Wreg[g][7], acc[g], 0, 0, 0);
        }

        int par = t & 1;
#pragma unroll
        for (int g = 0; g < 3; g++) {
            red[par][wave][g][lane]     = acc[g];
            red[par][wave][3 + g][lane] = xacc[g];
        }
        __syncthreads();

        float gh0 = red[par][0][0][Lp][reg] + red[par][1][0][Lp][reg] + red[par][2][0][Lp][reg] + red[par][3][0][Lp][reg];
        float gh1 = red[par][0][1][Lp][reg] + red[par][1][1][Lp][reg] + red[par][2][1][Lp][reg] + red[par][3][1][Lp][reg];
        float gh2 = red[par][0][2][Lp][reg] + red[par][1][2][Lp][reg] + red[par][2][2][Lp][reg] + red[par][3][2][Lp][reg];
        float xr  = red[par][0][3][Lp][reg] + red[par][1][3][Lp][reg] + red[par][2][3][Lp][reg] + red[par][3][3][Lp][reg];
        float xz  = red[par][0][4][Lp][reg] + red[par][1][4][Lp][reg] + red[par][2][4][Lp][reg] + red[par][3][4][Lp][reg];
        float xn  = red[par][0][5][Lp][reg] + red[par][1][5][Lp][reg] + red[par][2][5][Lp][reg] + red[par][3][5][Lp][reg];

        float r = sigmoid_f(xr + gh0 + bhr);
        float z = sigmoid_f(xz + gh1 + bhz);
        float n = tanh_f(xn + r * (gh2 + bhn));
        float hnew = n + z * (hreg - n);
        hreg = hnew;

        unsigned short hbv = f2bf(hnew);
        if (hbv == 0xAAAAu) hbv = 0xAAABu;   // never store the sentinel

        {
            unsigned short* hp = hist_t1 + (size_t)b * H_ + jg;
            unsigned hv32 = hbv;
            asm volatile("global_store_short %0, %1, off sc0 sc1"
                         :: "v"(hp), "v"(hv32) : "memory");
        }
        yB[((size_t)b * L_ + t) * H_ + jg] = hbv;   // cached; consumed after kernel end
    }
}

// ---- phase 3: logits[m][v] = y[m] @ Wout + bout   (M=16384, K=1024, N=256) ----
__global__ __launch_bounds__(256) void out_gemm(const unsigned short* __restrict__ yB,
                                                const unsigned short* __restrict__ WoutT,
                                                const float* __restrict__ bout,
                                                float* __restrict__ out) {
    int ntile = blockIdx.x;
    int mtile = blockIdx.y;
    int wave = threadIdx.x >> 6, lane = threadIdx.x & 63;
    int l16 = lane & 15, q = lane >> 4;

    int m = mtile * 64 + wave * 16 + l16;
    const bf16x8* Arow = (const bf16x8*)(yB + (size_t)m * H_);
    int n0 = ntile * 64;

    f32x4 acc[4] = {};
    for (int k0 = 0; k0 < H_; k0 += 32) {
        bf16x8 a = Arow[(k0 >> 3) + q];
#pragma unroll
        for (int j = 0; j < 4; j++) {
            const bf16x8* Brow = (const bf16x8*)(WoutT + (size_t)(n0 + j*16 + l16) * H_);
            bf16x8 b = Brow[(k0 >> 3) + q];
            acc[j] = __builtin_amdgcn_mfma_f32_16x16x32_bf16(a, b, acc[j], 0, 0, 0);
        }
    }
    int mrow = mtile * 64 + wave * 16 + q * 4;
#pragma unroll
    for (int j = 0; j < 4; j++) {
        int n = n0 + j * 16 + l16;
        float bias = bout[n];
#pragma unroll
        for (int r = 0; r < 4; r++)
            out[(size_t)(mrow + r) * V_ + n] = acc[j][r] + bias;
    }
}

extern "C" void kernel_launch(void* const* d_in, const int* in_sizes, int n_in,
                              void* d_out, int out_size, void* d_ws, size_t ws_size,
                              hipStream_t stream) {
    const int*   tokens = (const int*)  d_in[0];
    const float* emb    = (const float*)d_in[1];
    const float* Wi     = (const float*)d_in[2];
    const float* Wh     = (const float*)d_in[3];
    const float* bh     = (const float*)d_in[4];
    const float* Wout   = (const float*)d_in[5];
    const float* bout   = (const float*)d_in[6];
    float* out = (float*)d_out;

    char* ws = (char*)d_ws;
    size_t off = 0;
    auto alloc = [&](size_t bytes) -> void* {
        void* p = ws + off;
        off += (bytes + 255) & ~(size_t)255;
        return p;
    };
    unsigned short* WhT   = (unsigned short*)alloc((size_t)H3 * H_ * 2);   // 6 MB
    unsigned short* WiT   = (unsigned short*)alloc((size_t)H3 * E_ * 2);   // 1.5 MB
    unsigned short* WoutT = (unsigned short*)alloc((size_t)V_ * H_ * 2);   // 0.5 MB
    unsigned short* embB  = (unsigned short*)alloc((size_t)V_ * E_ * 2);   // 128 KB
    unsigned short* yB    = (unsigned short*)alloc((size_t)B_ * L_ * H_ * 2); // 32 MB
    unsigned short* hist  = (unsigned short*)alloc((size_t)(L_ + 1) * B_ * H_ * 2); // 33.7 MB

    prep_all<<<12544, 256, 0, stream>>>(Wh, Wi, Wout, emb, WhT, WiT, WoutT,
                                        embB, hist, (uint4*)(hist + (size_t)B_ * H_));

    {
        unsigned short* ah = hist;
        const unsigned short* aW = WhT; const unsigned short* aWx = WiT;
        const unsigned short* ae = embB; const int* at = tokens;
        const float* ab = bh; unsigned short* ay = yB;
        void* args[] = {&ah, &aW, &aWx, &ae, &at, &ab, &ay};
        hipError_t err = hipLaunchCooperativeKernel((void*)gru_persistent,
                                                    dim3(256), dim3(256), args, 0, stream);
        if (err != hipSuccess) {
            // fallback: plain launch; 256 blocks at 1 block/CU co-reside on 256 CUs,
            // and all spins are bounded (fail loud via absmax, not hang)
            gru_persistent<<<dim3(256), dim3(256), 0, stream>>>(
                ah, aW, aWx, ae, at, ab, ay);
        }
    }

    out_gemm<<<dim3(4, 256), 256, 0, stream>>>(yB, WoutT, bout, out);
}

// Round 7
// 939.088 us; speedup vs baseline: 1.7884x; 1.4869x over previous
//
#include <hip/hip_runtime.h>
#include <cstdint>
#include <math.h>

#define B_  64
#define L_  256
#define V_  256
#define E_  256
#define H_  1024
#define H3  3072

typedef __bf16 bf16x8 __attribute__((ext_vector_type(8)));
typedef float  f32x4  __attribute__((ext_vector_type(4)));

__device__ __forceinline__ unsigned short f2bf(float f) {
    union { float f; unsigned u; } v; v.f = f;
    unsigned r = v.u + 0x7fffu + ((v.u >> 16) & 1u);   // round-to-nearest-even
    return (unsigned short)(r >> 16);
}

// ok iff NO 16-bit half of any dword equals the 0xAAAA poison sentinel
__device__ __forceinline__ int chunk_ok(bf16x8 v) {
    union { bf16x8 b; unsigned u[4]; } cv; cv.b = v;
    int ok = 1;
#pragma unroll
    for (int i = 0; i < 4; i++) {
        unsigned x = cv.u[i] ^ 0xAAAAAAAAu;
        ok &= (int)((x & 0xFFFFu) != 0u) & (int)((x >> 16) != 0u);
    }
    return ok;
}

__device__ __forceinline__ float sigmoid_f(float x) {
    return __builtin_amdgcn_rcpf(1.0f + __expf(-x));
}
__device__ __forceinline__ float tanh_f(float x) {
    // tanh(x) = 1 - 2/(e^{2x}+1); saturates correctly at +-inf
    return 1.0f - 2.0f * __builtin_amdgcn_rcpf(1.0f + __expf(2.0f * x));
}

// ---- single prep kernel: 3 transposes + emb convert + h0 zero + hist poison ----
// grid regions: [0,3072) WhT tiles; [3072,3840) WiT; [3840,4096) WoutT;
// [4096,4352) embB+h0; [4352,12544) poison slots 1..256.
__global__ __launch_bounds__(256) void prep_all(
        const float* __restrict__ Wh, const float* __restrict__ Wi,
        const float* __restrict__ Wout, const float* __restrict__ emb,
        unsigned short* __restrict__ WhT, unsigned short* __restrict__ WiT,
        unsigned short* __restrict__ WoutT, unsigned short* __restrict__ embB,
        unsigned short* __restrict__ h0b, uint4* __restrict__ poison) {
    __shared__ unsigned short tile[32][34];
    int bid = blockIdx.x;
    const float* src; unsigned short* dst; int rows, cols, nt, kt;
    if (bid < 3072)      { src = Wh;   dst = WhT;   rows = H_; cols = H3; nt = bid % 96; kt = bid / 96; }
    else if (bid < 3840) { int b = bid - 3072; src = Wi;   dst = WiT;   rows = E_; cols = H3; nt = b % 96; kt = b / 96; }
    else if (bid < 4096) { int b = bid - 3840; src = Wout; dst = WoutT; rows = H_; cols = V_; nt = b % 8;  kt = b / 8; }
    else if (bid < 4352) {
        int idx = (bid - 4096) * 256 + threadIdx.x;   // 65536 = V*E = B*H
        embB[idx] = f2bf(emb[idx]);
        h0b[idx]  = 0;
        return;
    } else {
        size_t T = (size_t)(bid - 4352) * 256 + threadIdx.x;   // 2M uint4 = 33.55 MB
        uint4 v; v.x = v.y = v.z = v.w = 0xAAAAAAAAu;
        poison[T] = v;
        return;
    }
    int n0 = nt * 32, k0 = kt * 32;
    int tx = threadIdx.x & 31, ty = threadIdx.x >> 5;
#pragma unroll
    for (int j = 0; j < 32; j += 8)
        tile[tx][ty + j] = f2bf(src[(size_t)(k0 + ty + j) * cols + (n0 + tx)]);
    __syncthreads();
#pragma unroll
    for (int j = 0; j < 32; j += 8)
        dst[(size_t)(n0 + ty + j) * rows + (k0 + tx)] = tile[ty + j][tx];
}

// ---- phase 2: persistent GRU; round-0 structure, poll semantics and phase
//      alignment EXACTLY; the only delta vs round-0 is rcp-based activations
//      (pure VALU, after the poll, phase-preserving). ----
__global__ __launch_bounds__(256, 1) void gru_persistent(
        unsigned short* __restrict__ hist,        // [257][B][H], slot0=0, rest poisoned
        const unsigned short* __restrict__ WhT,   // [3H][H]
        const unsigned short* __restrict__ WiT,   // [3H][E]
        const unsigned short* __restrict__ embB,  // [V][E]
        const int* __restrict__ tokens,           // [B][L]
        const float* __restrict__ bh,
        unsigned short* __restrict__ yB) {        // [B][L][H]
    __shared__ f32x4 red[2][4][6][64];            // [parity][wave][slot][lane]

    int bid = blockIdx.x;
    int btile = bid & 3;
    int jtile = bid >> 2;
    int wave = threadIdx.x >> 6, lane = threadIdx.x & 63;
    int l16 = lane & 15, q = lane >> 4;
    int b0 = btile * 16, j0 = jtile * 16;
    int kbase = wave * 256;

    // ---- pin Wh fragments (96 VGPR/lane) ----
    bf16x8 Wreg[3][8];
#pragma unroll
    for (int g = 0; g < 3; g++) {
        const bf16x8* Brow = (const bf16x8*)(WhT + (size_t)(g * H_ + j0 + l16) * H_);
#pragma unroll
        for (int kk = 0; kk < 8; kk++) {
            Wreg[g][kk] = Brow[(kbase >> 3) + kk * 4 + q];
            asm volatile("" : "+v"(Wreg[g][kk]));
        }
    }
    // ---- pin Wi fragments (24 VGPR/lane) ----
    bf16x8 Wxreg[3][2];
#pragma unroll
    for (int g = 0; g < 3; g++) {
        const bf16x8* Bx = (const bf16x8*)(WiT + (size_t)(g * H_ + j0 + l16) * E_);
#pragma unroll
        for (int c = 0; c < 2; c++) {
            Wxreg[g][c] = Bx[wave * 8 + c * 4 + q];
            asm volatile("" : "+v"(Wxreg[g][c]));
        }
    }

    // ---- per-thread gate mapping / biases / fp32 state ----
    int Lp  = threadIdx.x & 63;
    int reg = threadIdx.x >> 6;
    int b_local = (Lp >> 4) * 4 + reg;
    int j_local = Lp & 15;
    int b = b0 + b_local, jg = j0 + j_local;
    float bhr = bh[jg];
    float bhz = bh[H_ + jg];
    float bhn = bh[2 * H_ + jg];
    asm volatile("" : "+v"(bhr), "+v"(bhz), "+v"(bhn));
    float hreg = 0.0f;

    const int tokrow = (b0 + l16) * L_;

    for (int t = 0; t < L_; t++) {
        const unsigned short* hist_t  = hist + (size_t)t * (B_ * H_);
        unsigned short*       hist_t1 = hist + (size_t)(t + 1) * (B_ * H_);

        // ---- xw partials (h-independent; before the poll) ----
        int tok = tokens[tokrow + t];
        const bf16x8* Ax = (const bf16x8*)(embB + (size_t)tok * E_);
        bf16x8 ax0 = Ax[wave * 8 + q];
        bf16x8 ax1 = Ax[wave * 8 + 4 + q];
        f32x4 xacc[3] = {};
#pragma unroll
        for (int g = 0; g < 3; g++) {
            xacc[g] = __builtin_amdgcn_mfma_f32_16x16x32_bf16(ax0, Wxreg[g][0], xacc[g], 0, 0, 0);
            xacc[g] = __builtin_amdgcn_mfma_f32_16x16x32_bf16(ax1, Wxreg[g][1], xacc[g], 0, 0, 0);
        }

        const unsigned short* p = hist_t + (size_t)(b0 + l16) * H_ + kbase + q * 8;
        bf16x8 a0, a1, a2, a3, a4, a5, a6, a7;

        // ---- poll group A (chunks 0-3, 128 B); passing iteration = the data ----
        {
            int spins = 0;
            while (true) {
                asm volatile("global_load_dwordx4 %0, %1, off sc0 sc1" : "=v"(a0) : "v"(p));
                asm volatile("global_load_dwordx4 %0, %1, off sc0 sc1" : "=v"(a1) : "v"(p + 32));
                asm volatile("global_load_dwordx4 %0, %1, off sc0 sc1" : "=v"(a2) : "v"(p + 64));
                asm volatile("global_load_dwordx4 %0, %1, off sc0 sc1" : "=v"(a3) : "v"(p + 96));
                asm volatile("s_waitcnt vmcnt(0)"
                             : "+v"(a0), "+v"(a1), "+v"(a2), "+v"(a3) :: "memory");
                int ok = chunk_ok(a0) & chunk_ok(a1) & chunk_ok(a2) & chunk_ok(a3);
                if (__all(ok)) break;
                if (++spins > (1 << 18)) break;   // fail loud, never hang
                __builtin_amdgcn_s_sleep(1);
            }
        }
        // ---- issue group B loads; overlap with group-A MFMAs ----
        asm volatile("global_load_dwordx4 %0, %1, off sc0 sc1" : "=v"(a4) : "v"(p + 128));
        asm volatile("global_load_dwordx4 %0, %1, off sc0 sc1" : "=v"(a5) : "v"(p + 160));
        asm volatile("global_load_dwordx4 %0, %1, off sc0 sc1" : "=v"(a6) : "v"(p + 192));
        asm volatile("global_load_dwordx4 %0, %1, off sc0 sc1" : "=v"(a7) : "v"(p + 224));

        f32x4 acc[3] = {};
#pragma unroll
        for (int g = 0; g < 3; g++) {
            acc[g] = __builtin_amdgcn_mfma_f32_16x16x32_bf16(a0, Wreg[g][0], acc[g], 0, 0, 0);
            acc[g] = __builtin_amdgcn_mfma_f32_16x16x32_bf16(a1, Wreg[g][1], acc[g], 0, 0, 0);
            acc[g] = __builtin_amdgcn_mfma_f32_16x16x32_bf16(a2, Wreg[g][2], acc[g], 0, 0, 0);
            acc[g] = __builtin_amdgcn_mfma_f32_16x16x32_bf16(a3, Wreg[g][3], acc[g], 0, 0, 0);
        }

        // ---- wait + check group B; retry only B on miss ----
        asm volatile("s_waitcnt vmcnt(0)"
                     : "+v"(a4), "+v"(a5), "+v"(a6), "+v"(a7) :: "memory");
        {
            int ok = chunk_ok(a4) & chunk_ok(a5) & chunk_ok(a6) & chunk_ok(a7);
            if (!__all(ok)) {
                int spins = 0;
                while (true) {
                    __builtin_amdgcn_s_sleep(1);
                    asm volatile("global_load_dwordx4 %0, %1, off sc0 sc1" : "=v"(a4) : "v"(p + 128));
                    asm volatile("global_load_dwordx4 %0, %1, off sc0 sc1" : "=v"(a5) : "v"(p + 160));
                    asm volatile("global_load_dwordx4 %0, %1, off sc0 sc1" : "=v"(a6) : "v"(p + 192));
                    asm volatile("global_load_dwordx4 %0, %1, off sc0 sc1" : "=v"(a7) : "v"(p + 224));
                    asm volatile("s_waitcnt vmcnt(0)"
                                 : "+v"(a4), "+v"(a5), "+v"(a6), "+v"(a7) :: "memory");
                    int ok2 = chunk_ok(a4) & chunk_ok(a5) & chunk_ok(a6) & chunk_ok(a7);
                    if (__all(ok2)) break;
                    if (++spins > (1 << 18)) break;
                }
            }
        }
#pragma unroll
        for (int g = 0; g < 3; g++) {
            acc[g] = __builtin_amdgcn_mfma_f32_16x16x32_bf16(a4, Wreg[g][4], acc[g], 0, 0, 0);
            acc[g] = __builtin_amdgcn_mfma_f32_16x16x32_bf16(a5, Wreg[g][5], acc[g], 0, 0, 0);
            acc[g] = __builtin_amdgcn_mfma_f32_16x16x32_bf16(a6, Wreg[g][6], acc[g], 0, 0, 0);
            acc[g] = __builtin_amdgcn_mfma_f32_16x16x32_bf16(a7, Wreg[g][7], acc[g], 0, 0, 0);
        }

        int par = t & 1;
#pragma unroll
        for (int g = 0; g < 3; g++) {
            red[par][wave][g][lane]     = acc[g];
            red[par][wave][3 + g][lane] = xacc[g];
        }
        __syncthreads();

        float gh0 = red[par][0][0][Lp][reg] + red[par][1][0][Lp][reg] + red[par][2][0][Lp][reg] + red[par][3][0][Lp][reg];
        float gh1 = red[par][0][1][Lp][reg] + red[par][1][1][Lp][reg] + red[par][2][1][Lp][reg] + red[par][3][1][Lp][reg];
        float gh2 = red[par][0][2][Lp][reg] + red[par][1][2][Lp][reg] + red[par][2][2][Lp][reg] + red[par][3][2][Lp][reg];
        float xr  = red[par][0][3][Lp][reg] + red[par][1][3][Lp][reg] + red[par][2][3][Lp][reg] + red[par][3][3][Lp][reg];
        float xz  = red[par][0][4][Lp][reg] + red[par][1][4][Lp][reg] + red[par][2][4][Lp][reg] + red[par][3][4][Lp][reg];
        float xn  = red[par][0][5][Lp][reg] + red[par][1][5][Lp][reg] + red[par][2][5][Lp][reg] + red[par][3][5][Lp][reg];

        float r = sigmoid_f(xr + gh0 + bhr);
        float z = sigmoid_f(xz + gh1 + bhz);
        float n = tanh_f(xn + r * (gh2 + bhn));
        float hnew = n + z * (hreg - n);
        hreg = hnew;

        unsigned short hbv = f2bf(hnew);
        if (hbv == 0xAAAAu) hbv = 0xAAABu;   // never store the sentinel

        {
            unsigned short* hp = hist_t1 + (size_t)b * H_ + jg;
            unsigned hv32 = hbv;
            asm volatile("global_store_short %0, %1, off sc0 sc1"
                         :: "v"(hp), "v"(hv32) : "memory");
        }
        yB[((size_t)b * L_ + t) * H_ + jg] = hbv;   // cached; consumed after kernel end
    }
}

// ---- phase 3: logits[m][v] = y[m] @ Wout + bout   (M=16384, K=1024, N=256) ----
__global__ __launch_bounds__(256) void out_gemm(const unsigned short* __restrict__ yB,
                                                const unsigned short* __restrict__ WoutT,
                                                const float* __restrict__ bout,
                                                float* __restrict__ out) {
    int ntile = blockIdx.x;
    int mtile = blockIdx.y;
    int wave = threadIdx.x >> 6, lane = threadIdx.x & 63;
    int l16 = lane & 15, q = lane >> 4;

    int m = mtile * 64 + wave * 16 + l16;
    const bf16x8* Arow = (const bf16x8*)(yB + (size_t)m * H_);
    int n0 = ntile * 64;

    f32x4 acc[4] = {};
    for (int k0 = 0; k0 < H_; k0 += 32) {
        bf16x8 a = Arow[(k0 >> 3) + q];
#pragma unroll
        for (int j = 0; j < 4; j++) {
            const bf16x8* Brow = (const bf16x8*)(WoutT + (size_t)(n0 + j*16 + l16) * H_);
            bf16x8 b = Brow[(k0 >> 3) + q];
            acc[j] = __builtin_amdgcn_mfma_f32_16x16x32_bf16(a, b, acc[j], 0, 0, 0);
        }
    }
    int mrow = mtile * 64 + wave * 16 + q * 4;
#pragma unroll
    for (int j = 0; j < 4; j++) {
        int n = n0 + j * 16 + l16;
        float bias = bout[n];
#pragma unroll
        for (int r = 0; r < 4; r++)
            out[(size_t)(mrow + r) * V_ + n] = acc[j][r] + bias;
    }
}

extern "C" void kernel_launch(void* const* d_in, const int* in_sizes, int n_in,
                              void* d_out, int out_size, void* d_ws, size_t ws_size,
                              hipStream_t stream) {
    const int*   tokens = (const int*)  d_in[0];
    const float* emb    = (const float*)d_in[1];
    const float* Wi     = (const float*)d_in[2];
    const float* Wh     = (const float*)d_in[3];
    const float* bh     = (const float*)d_in[4];
    const float* Wout   = (const float*)d_in[5];
    const float* bout   = (const float*)d_in[6];
    float* out = (float*)d_out;

    char* ws = (char*)d_ws;
    size_t off = 0;
    auto alloc = [&](size_t bytes) -> void* {
        void* p = ws + off;
        off += (bytes + 255) & ~(size_t)255;
        return p;
    };
    unsigned short* WhT   = (unsigned short*)alloc((size_t)H3 * H_ * 2);   // 6 MB
    unsigned short* WiT   = (unsigned short*)alloc((size_t)H3 * E_ * 2);   // 1.5 MB
    unsigned short* WoutT = (unsigned short*)alloc((size_t)V_ * H_ * 2);   // 0.5 MB
    unsigned short* embB  = (unsigned short*)alloc((size_t)V_ * E_ * 2);   // 128 KB
    unsigned short* yB    = (unsigned short*)alloc((size_t)B_ * L_ * H_ * 2); // 32 MB
    unsigned short* hist  = (unsigned short*)alloc((size_t)(L_ + 1) * B_ * H_ * 2); // 33.7 MB

    prep_all<<<12544, 256, 0, stream>>>(Wh, Wi, Wout, emb, WhT, WiT, WoutT,
                                        embB, hist, (uint4*)(hist + (size_t)B_ * H_));

    {
        unsigned short* ah = hist;
        const unsigned short* aW = WhT; const unsigned short* aWx = WiT;
        const unsigned short* ae = embB; const int* at = tokens;
        const float* ab = bh; unsigned short* ay = yB;
        void* args[] = {&ah, &aW, &aWx, &ae, &at, &ab, &ay};
        hipError_t err = hipLaunchCooperativeKernel((void*)gru_persistent,
                                                    dim3(256), dim3(256), args, 0, stream);
        if (err != hipSuccess) {
            // fallback: plain launch; 256 blocks at 1 block/CU co-reside on 256 CUs,
            // and all spins are bounded (fail loud via absmax, not hang)
            gru_persistent<<<dim3(256), dim3(256), 0, stream>>>(
                ah, aW, aWx, ae, at, ab, ay);
        }
    }

    out_gemm<<<dim3(4, 256), 256, 0, stream>>>(yB, WoutT, bout, out);
}